// Round 6
// baseline (454.875 us; speedup 1.0000x reference)
//
#include <hip/hip_runtime.h>

// InteractLayer via bf16 MFMA (16x16x32). B=16384 batches, F=32, D=64, H=64 (2 heads x 32).
// Pre-kernel: W (4x [64x64] f32) -> bf16 transposed Wt[e][d] in d_ws.
// PERSISTENT version: grid = B/NB blocks; each block loops over NB=8 batches.
//  - bfrag (projection weights) loaded once per wave, live across the loop.
//  - T14 async-stage split: X tile for iter i+1 is global-loaded into regs during
//    iter i's phase 1 and written to LDS after the post-compute barrier (B3), so
//    the HBM latency hides under ~2000 cycles of phase-2/3 work.
// Per iteration (phases identical to verified round-4 kernel):
//  B1: X staged -> phase1: Q,K row-major; V,R transposed [e][tok] packed writes;
//  B2: QKV ready -> phase2: QK^T + exp (no max-sub, no cross-lane), P into s_xp
//  (aliased over dead X); phase3 (no barrier, same-wave P rows): PV, rowsum via
//  all-ones MFMA, rcp-normalize, +residual, relu, store. B3: LDS reads drained.
// LDS: 5 x 4096 B unpadded = 20480 B -> 8 blocks/CU; 16B-block XOR swizzles
// replace padding (hot b128 reads 2-way = free). VGPR capped via (256,8) so wave
// slots don't halve at the 64-VGPR boundary (round-3 mechanism; round-4 verified
// the allocator offloads accumulators to AGPRs under this cap without spilling).

constexpr int kF = 32, kD = 64, kH = 64;
constexpr int NB = 8;                   // batches per persistent block

using short8   = __attribute__((ext_vector_type(8))) short;
using float4v  = __attribute__((ext_vector_type(4))) float;
using ushort4v = __attribute__((ext_vector_type(4))) unsigned short;

__device__ __forceinline__ unsigned short f2bf(float x) {
    return __builtin_bit_cast(unsigned short, (__bf16)x);   // native RNE convert
}
__device__ __forceinline__ float bf2f(unsigned short b) {
    return __uint_as_float((unsigned)b << 16);
}
// 16B-block XOR swizzles. Pure function of (row, blk): applied identically on every
// write and read of the same logical element -> bijective & consistent.
__device__ __forceinline__ int sw64(int row, int blk) {   // rows of 64 elems (8 blocks)
    return blk ^ ((row ^ (row >> 1)) & 7);
}
__device__ __forceinline__ int sw32(int row, int blk) {   // rows of 32 elems (4 blocks)
    return blk ^ ((row ^ (row >> 2)) & 3);
}

__global__ void wprep_kernel(const float* __restrict__ Wq, const float* __restrict__ Wk,
                             const float* __restrict__ Wv, const float* __restrict__ Wr,
                             unsigned short* __restrict__ wt) {
    const int m = blockIdx.x;               // 0..3 : Q,K,V,R
    const float* __restrict__ W = (m == 0) ? Wq : (m == 1) ? Wk : (m == 2) ? Wv : Wr;
    for (int i = threadIdx.x; i < kD * kH; i += blockDim.x) {
        const int e = i >> 6, d = i & 63;
        wt[m * kD * kH + e * kD + d] = f2bf(W[d * kH + e]);   // transposed: Wt[e][d]
    }
}

__global__ __launch_bounds__(256, 8)
void interact_mfma(const float* __restrict__ X, const unsigned short* __restrict__ Wt,
                   float* __restrict__ out)
{
    // s_xp: X staging [32 tok][64 d] (swizzled) during B1..phase1; reused as
    // P [64 rows][32 cols] in phases 2-3. 5 x 2048 elems = 20480 B total.
    __shared__ __align__(16) unsigned short s_xp[2048];
    __shared__ __align__(16) unsigned short s_q [2048];   // Q[tok][e]
    __shared__ __align__(16) unsigned short s_k [2048];   // K[tok][e]
    __shared__ __align__(16) unsigned short s_vt[2048];   // Vt[e][tok]
    __shared__ __align__(16) unsigned short s_rt[2048];   // Rt[e][tok]

    const int t    = threadIdx.x;
    const int w    = t >> 6;        // wave 0..3
    const int lane = t & 63;
    const int quad = lane >> 4;     // 0..3
    const int l    = lane & 15;
    const int h    = w >> 1;        // head (phases 2/3)
    const int wmt  = w & 1;         // row-block (phases 2/3)
    const int b0   = blockIdx.x * NB;

    // staging decomposition for this thread's two float4 chunks (fixed all iters)
    const int f0 = t >> 4,          c0 = t & 15;          // idx = t
    const int f1 = (256 + t) >> 4,  c1 = t & 15;          // idx = 256 + t

    // ---- bfrag: projection-w weights, loaded ONCE (live across the loop) ----
    // B[k=d][n=e] frag: lane holds Wt[e = 16*nt + l][d = 32*ks + quad*8 + j]
    short8 bfrag[4][2];
    {
        const unsigned short* __restrict__ wtm = Wt + w * (kD * kH);
        #pragma unroll
        for (int nt = 0; nt < 4; ++nt)
            #pragma unroll
            for (int ks = 0; ks < 2; ++ks)
                bfrag[nt][ks] =
                    *reinterpret_cast<const short8*>(wtm + (16 * nt + l) * kD + 32 * ks + quad * 8);
    }

    // ---- prologue: load + stage X_{b0} ----
    float4 xv0, xv1;
    {
        const float* __restrict__ Xb = X + (size_t)b0 * (kF * kD);
        xv0 = reinterpret_cast<const float4*>(Xb)[t];
        xv1 = reinterpret_cast<const float4*>(Xb)[256 + t];
        ushort4v p0 = { f2bf(xv0.x), f2bf(xv0.y), f2bf(xv0.z), f2bf(xv0.w) };
        ushort4v p1 = { f2bf(xv1.x), f2bf(xv1.y), f2bf(xv1.z), f2bf(xv1.w) };
        *reinterpret_cast<ushort4v*>(&s_xp[f0 * 64 + sw64(f0, c0 >> 1) * 8 + (c0 & 1) * 4]) = p0;
        *reinterpret_cast<ushort4v*>(&s_xp[f1 * 64 + sw64(f1, c1 >> 1) * 8 + (c1 & 1) * 4]) = p1;
    }

    for (int it = 0; it < NB; ++it) {
        const int b = b0 + it;
        __syncthreads();                                  // B1: X_it staged

        // ---- phase 1: projection w: Out[32x64] = X[32x64] @ W_w[64x64] ----
        {
            // A[m = 16*mt + l][k = 32*ks + quad*8 + j]  (swizzled read, 2-way banks)
            short8 afrag[2][2];
            #pragma unroll
            for (int mt = 0; mt < 2; ++mt)
                #pragma unroll
                for (int ks = 0; ks < 2; ++ks) {
                    const int row = 16 * mt + l;
                    afrag[mt][ks] = *reinterpret_cast<const short8*>(
                        &s_xp[row * 64 + sw64(row, 4 * ks + quad) * 8]);
                }

            // prefetch X_{it+1} into regs (T14 issue-early; LDS write after B3)
            if (it + 1 < NB) {
                const float* __restrict__ Xn = X + (size_t)(b + 1) * (kF * kD);
                xv0 = reinterpret_cast<const float4*>(Xn)[t];
                xv1 = reinterpret_cast<const float4*>(Xn)[256 + t];
            }

            float4v acc[2][4];
            #pragma unroll
            for (int mt = 0; mt < 2; ++mt)
                #pragma unroll
                for (int nt = 0; nt < 4; ++nt)
                    acc[mt][nt] = (float4v){0.f, 0.f, 0.f, 0.f};

            #pragma unroll
            for (int mt = 0; mt < 2; ++mt)
                #pragma unroll
                for (int nt = 0; nt < 4; ++nt) {
                    acc[mt][nt] = __builtin_amdgcn_mfma_f32_16x16x32_bf16(
                        afrag[mt][0], bfrag[nt][0], acc[mt][nt], 0, 0, 0);
                    acc[mt][nt] = __builtin_amdgcn_mfma_f32_16x16x32_bf16(
                        afrag[mt][1], bfrag[nt][1], acc[mt][nt], 0, 0, 0);
                }

            // C/D layout: element (reg r, lane) = Out[16*mt + quad*4 + r][16*nt + l]
            if (w < 2) {
                // Q,K: row-major [tok][e]
                unsigned short* __restrict__ dst = (w == 0) ? s_q : s_k;
                #pragma unroll
                for (int mt = 0; mt < 2; ++mt)
                    #pragma unroll
                    for (int nt = 0; nt < 4; ++nt)
                        #pragma unroll
                        for (int r = 0; r < 4; ++r) {
                            const int row = 16 * mt + quad * 4 + r;   // tok
                            dst[row * 64 + sw64(row, 2 * nt + (l >> 3)) * 8 + (l & 7)] =
                                f2bf(acc[mt][nt][r]);
                        }
            } else {
                // V,R: transposed [e][tok] -> reg index r contiguous -> packed 8B writes
                unsigned short* __restrict__ dstT = (w == 2) ? s_vt : s_rt;
                #pragma unroll
                for (int mt = 0; mt < 2; ++mt)
                    #pragma unroll
                    for (int nt = 0; nt < 4; ++nt) {
                        const int e = 16 * nt + l;
                        ushort4v pk = { f2bf(acc[mt][nt][0]), f2bf(acc[mt][nt][1]),
                                        f2bf(acc[mt][nt][2]), f2bf(acc[mt][nt][3]) };
                        *reinterpret_cast<ushort4v*>(
                            &dstT[e * 32 + sw32(e, 2 * mt + (quad >> 1)) * 8 + (quad & 1) * 4]) = pk;
                    }
            }
        }
        __syncthreads();                                  // B2: QKV(R) ready

        // ---- phase 2: scores + exp. No max-subtraction, no cross-lane ops. ----
        {
            const int qrow = 16 * wmt + l;
            const short8 qa = *reinterpret_cast<const short8*>(
                &s_q[qrow * 64 + sw64(qrow, 4 * h + quad) * 8]);
            const short8 kb0 = *reinterpret_cast<const short8*>(
                &s_k[l * 64 + sw64(l, 4 * h + quad) * 8]);
            const short8 kb1 = *reinterpret_cast<const short8*>(
                &s_k[(16 + l) * 64 + sw64(16 + l, 4 * h + quad) * 8]);

            float4v s0 = (float4v){0.f, 0.f, 0.f, 0.f};
            float4v s1 = (float4v){0.f, 0.f, 0.f, 0.f};
            s0 = __builtin_amdgcn_mfma_f32_16x16x32_bf16(qa, kb0, s0, 0, 0, 0);
            s1 = __builtin_amdgcn_mfma_f32_16x16x32_bf16(qa, kb1, s1, 0, 0, 0);

            // row (16*wmt+quad*4+r): its 32 scores live in this quad's 16 lanes x {s0,s1}
            #pragma unroll
            for (int r = 0; r < 4; ++r) {
                const int rowG = h * kF + 16 * wmt + quad * 4 + r;
                s_xp[rowG * 32 + sw32(rowG, l >> 3) * 8 + (l & 7)]       = f2bf(__expf(s0[r]));
                s_xp[rowG * 32 + sw32(rowG, 2 + (l >> 3)) * 8 + (l & 7)] = f2bf(__expf(s1[r]));
            }
        }
        // NO barrier: phase 3 reads only P rows written by this same wave
        // (rows h*32+16*wmt .. +15); s_vt/s_rt were written before B2.

        // ---- phase 3: O_h = P_h @ V_h; rowsum via all-ones MFMA; +R, relu, store ----
        {
            const int prow = h * kF + 16 * wmt + l;
            const short8 pa = *reinterpret_cast<const short8*>(
                &s_xp[prow * 32 + sw32(prow, quad) * 8]);
            const short8 vb0 = *reinterpret_cast<const short8*>(
                &s_vt[(32 * h + l) * 32 + sw32(32 * h + l, quad) * 8]);
            const short8 vb1 = *reinterpret_cast<const short8*>(
                &s_vt[(32 * h + 16 + l) * 32 + sw32(32 * h + 16 + l, quad) * 8]);
            const short8 ones = (short8)(short)0x3F80;   // bf16 1.0 splat

            float4v o0 = (float4v){0.f, 0.f, 0.f, 0.f};
            float4v o1 = (float4v){0.f, 0.f, 0.f, 0.f};
            float4v os = (float4v){0.f, 0.f, 0.f, 0.f};
            o0 = __builtin_amdgcn_mfma_f32_16x16x32_bf16(pa, vb0, o0, 0, 0, 0);
            o1 = __builtin_amdgcn_mfma_f32_16x16x32_bf16(pa, vb1, o1, 0, 0, 0);
            os = __builtin_amdgcn_mfma_f32_16x16x32_bf16(pa, ones, os, 0, 0, 0);  // row sums

            // residual: Rt[e][tok] -> reg index r contiguous -> packed 8B reads
            const ushort4v rA = *reinterpret_cast<const ushort4v*>(
                &s_rt[(32 * h + l) * 32 +
                      sw32(32 * h + l, 2 * wmt + (quad >> 1)) * 8 + (quad & 1) * 4]);
            const ushort4v rB = *reinterpret_cast<const ushort4v*>(
                &s_rt[(32 * h + 16 + l) * 32 +
                      sw32(32 * h + 16 + l, 2 * wmt + (quad >> 1)) * 8 + (quad & 1) * 4]);

            float* __restrict__ Ob = out + (size_t)b * (kF * kH);
            #pragma unroll
            for (int r = 0; r < 4; ++r) {
                const int f = 16 * wmt + quad * 4 + r;
                const float inv = __builtin_amdgcn_rcpf(os[r]);
                Ob[f * kH + 32 * h + l]      = fmaxf(o0[r] * inv + bf2f(rA[r]), 0.0f);
                Ob[f * kH + 32 * h + 16 + l] = fmaxf(o1[r] * inv + bf2f(rB[r]), 0.0f);
            }
        }
        __syncthreads();                                  // B3: all LDS reads drained

        // stage prefetched X_{it+1} (compiler inserts vmcnt wait on xv regs)
        if (it + 1 < NB) {
            ushort4v p0 = { f2bf(xv0.x), f2bf(xv0.y), f2bf(xv0.z), f2bf(xv0.w) };
            ushort4v p1 = { f2bf(xv1.x), f2bf(xv1.y), f2bf(xv1.z), f2bf(xv1.w) };
            *reinterpret_cast<ushort4v*>(&s_xp[f0 * 64 + sw64(f0, c0 >> 1) * 8 + (c0 & 1) * 4]) = p0;
            *reinterpret_cast<ushort4v*>(&s_xp[f1 * 64 + sw64(f1, c1 >> 1) * 8 + (c1 & 1) * 4]) = p1;
        }
    }
}

extern "C" void kernel_launch(void* const* d_in, const int* in_sizes, int n_in,
                              void* d_out, int out_size, void* d_ws, size_t ws_size,
                              hipStream_t stream) {
    const float* X  = (const float*)d_in[0];
    const float* Wq = (const float*)d_in[1];
    const float* Wk = (const float*)d_in[2];
    const float* Wv = (const float*)d_in[3];
    const float* Wr = (const float*)d_in[4];
    float* out = (float*)d_out;
    unsigned short* wt = (unsigned short*)d_ws;   // 4*64*64*2 = 32 KiB

    wprep_kernel<<<4, 256, 0, stream>>>(Wq, Wk, Wv, Wr, wt);

    const int B = in_sizes[0] / (kF * kD);        // 16384
    interact_mfma<<<B / NB, 256, 0, stream>>>(X, wt, out);
}

// Round 7
// 449.112 us; speedup vs baseline: 1.0128x; 1.0128x over previous
//
#include <hip/hip_runtime.h>

// InteractLayer via bf16 MFMA (16x16x32). B=16384 batches, F=32, D=64, H=64 (2 heads x 32).
// Pre-kernel: W (4x [64x64] f32) -> bf16 transposed Wt[e][d] in d_ws.
// PERSISTENT, spill-free version (round-6 spilled bfrag/xv under the 64-VGPR cap:
// FETCH 65->638 MB was scratch reload traffic, not HBM streaming).
//  - __launch_bounds__(256, 6): 84-VGPR cap; 6 blocks/CU matches the measured
//    saturation point (4blk=180us, 5=118, 6=114, 8=120). bfrag stays resident.
//  - X double-buffered in LDS: stage X_{it+1} into s_x[cur^1] during phase 1
//    (no barrier needed, disjoint buffer); xv regs live only a few hundred cycles.
//  - P aliases s_x[cur] (X dead after the pre-B2 afrag reads).
//  - 2 barriers/iter: B1 = prev ph2/3 reads drained (incl. P rows in s_x[cur^1],
//    which this iter's staging overwrites) AND X_it staged (covered by prev B2);
//    B2 = Q/K/Vt/Rt published, all afrag reads done (so P may overwrite s_x[cur]).
// Phases identical to verified round-4 kernel: ph1 projections (Q,K row-major;
// V,R transposed packed b64); ph2 QK^T + exp (no max-sub, no cross-lane); ph3 PV,
// rowsum via all-ones MFMA, rcp-normalize, +residual, relu.
// LDS: 6 x 4096 B = 24576 B -> 6 blocks/CU. 16B-block XOR swizzles, unpadded.

constexpr int kF = 32, kD = 64, kH = 64;
constexpr int NB = 8;                   // batches per persistent block

using short8   = __attribute__((ext_vector_type(8))) short;
using float4v  = __attribute__((ext_vector_type(4))) float;
using ushort4v = __attribute__((ext_vector_type(4))) unsigned short;

__device__ __forceinline__ unsigned short f2bf(float x) {
    return __builtin_bit_cast(unsigned short, (__bf16)x);   // native RNE convert
}
__device__ __forceinline__ float bf2f(unsigned short b) {
    return __uint_as_float((unsigned)b << 16);
}
// 16B-block XOR swizzles. Pure function of (row, blk): applied identically on every
// write and read of the same logical element -> bijective & consistent.
__device__ __forceinline__ int sw64(int row, int blk) {   // rows of 64 elems (8 blocks)
    return blk ^ ((row ^ (row >> 1)) & 7);
}
__device__ __forceinline__ int sw32(int row, int blk) {   // rows of 32 elems (4 blocks)
    return blk ^ ((row ^ (row >> 2)) & 3);
}

__global__ void wprep_kernel(const float* __restrict__ Wq, const float* __restrict__ Wk,
                             const float* __restrict__ Wv, const float* __restrict__ Wr,
                             unsigned short* __restrict__ wt) {
    const int m = blockIdx.x;               // 0..3 : Q,K,V,R
    const float* __restrict__ W = (m == 0) ? Wq : (m == 1) ? Wk : (m == 2) ? Wv : Wr;
    for (int i = threadIdx.x; i < kD * kH; i += blockDim.x) {
        const int e = i >> 6, d = i & 63;
        wt[m * kD * kH + e * kD + d] = f2bf(W[d * kH + e]);   // transposed: Wt[e][d]
    }
}

__global__ __launch_bounds__(256, 6)
void interact_mfma(const float* __restrict__ X, const unsigned short* __restrict__ Wt,
                   float* __restrict__ out)
{
    // s_x: 2 ping-pong X/P buffers of 2048 elems. X tile [32 tok][64 d] (sw64);
    // after afrag reads, the current buffer is reused for P [64 rows][32 cols] (sw32).
    __shared__ __align__(16) unsigned short s_x [2 * 2048];
    __shared__ __align__(16) unsigned short s_q [2048];   // Q[tok][e]
    __shared__ __align__(16) unsigned short s_k [2048];   // K[tok][e]
    __shared__ __align__(16) unsigned short s_vt[2048];   // Vt[e][token]
    __shared__ __align__(16) unsigned short s_rt[2048];   // Rt[e][token]

    const int t    = threadIdx.x;
    const int w    = t >> 6;        // wave 0..3
    const int lane = t & 63;
    const int quad = lane >> 4;     // 0..3
    const int l    = lane & 15;
    const int h    = w >> 1;        // head (phases 2/3)
    const int wmt  = w & 1;         // row-block (phases 2/3)
    const int b0   = blockIdx.x * NB;

    // staging decomposition for this thread's two float4 chunks (fixed all iters)
    const int f0 = t >> 4,          c0 = t & 15;          // idx = t
    const int f1 = (256 + t) >> 4,  c1 = t & 15;          // idx = 256 + t
    const int o0s = f0 * 64 + sw64(f0, c0 >> 1) * 8 + (c0 & 1) * 4;
    const int o1s = f1 * 64 + sw64(f1, c1 >> 1) * 8 + (c1 & 1) * 4;

    // ---- bfrag: projection-w weights, loaded ONCE (live across the loop) ----
    // B[k=d][n=e] frag: lane holds Wt[e = 16*nt + l][d = 32*ks + quad*8 + j]
    short8 bfrag[4][2];
    {
        const unsigned short* __restrict__ wtm = Wt + w * (kD * kH);
        #pragma unroll
        for (int nt = 0; nt < 4; ++nt)
            #pragma unroll
            for (int ks = 0; ks < 2; ++ks)
                bfrag[nt][ks] =
                    *reinterpret_cast<const short8*>(wtm + (16 * nt + l) * kD + 32 * ks + quad * 8);
    }

    // ---- prologue: load + stage X_{b0} into buffer 0 ----
    {
        const float* __restrict__ Xb = X + (size_t)b0 * (kF * kD);
        const float4 xv0 = reinterpret_cast<const float4*>(Xb)[t];
        const float4 xv1 = reinterpret_cast<const float4*>(Xb)[256 + t];
        ushort4v p0 = { f2bf(xv0.x), f2bf(xv0.y), f2bf(xv0.z), f2bf(xv0.w) };
        ushort4v p1 = { f2bf(xv1.x), f2bf(xv1.y), f2bf(xv1.z), f2bf(xv1.w) };
        *reinterpret_cast<ushort4v*>(&s_x[o0s]) = p0;
        *reinterpret_cast<ushort4v*>(&s_x[o1s]) = p1;
    }

    int cur = 0;
    for (int it = 0; it < NB; ++it) {
        const int b = b0 + it;
        unsigned short* __restrict__ sx_cur = s_x + cur * 2048;   // X_it, then P
        unsigned short* __restrict__ sx_nxt = s_x + (cur ^ 1) * 2048;

        // B1: prev ph2/3 LDS reads drained (P in sx_nxt about to be overwritten;
        // Q/K/Vt/Rt about to be rewritten). X_it staging was published by prev B2.
        __syncthreads();

        // ---- phase 1: projection w: Out[32x64] = X[32x64] @ W_w[64x64] ----
        {
            // prefetch X_{it+1}: issue global loads FIRST (latency hides under MFMA)
            float4 xv0, xv1;
            const bool pf = (it + 1 < NB);
            if (pf) {
                const float* __restrict__ Xn = X + (size_t)(b + 1) * (kF * kD);
                xv0 = reinterpret_cast<const float4*>(Xn)[t];
                xv1 = reinterpret_cast<const float4*>(Xn)[256 + t];
            }

            // A[m = 16*mt + l][k = 32*ks + quad*8 + j]  (swizzled read, 2-way banks)
            short8 afrag[2][2];
            #pragma unroll
            for (int mt = 0; mt < 2; ++mt)
                #pragma unroll
                for (int ks = 0; ks < 2; ++ks) {
                    const int row = 16 * mt + l;
                    afrag[mt][ks] = *reinterpret_cast<const short8*>(
                        &sx_cur[row * 64 + sw64(row, 4 * ks + quad) * 8]);
                }

            float4v acc[2][4];
            #pragma unroll
            for (int mt = 0; mt < 2; ++mt)
                #pragma unroll
                for (int nt = 0; nt < 4; ++nt)
                    acc[mt][nt] = (float4v){0.f, 0.f, 0.f, 0.f};

            #pragma unroll
            for (int mt = 0; mt < 2; ++mt)
                #pragma unroll
                for (int nt = 0; nt < 4; ++nt) {
                    acc[mt][nt] = __builtin_amdgcn_mfma_f32_16x16x32_bf16(
                        afrag[mt][0], bfrag[nt][0], acc[mt][nt], 0, 0, 0);
                    acc[mt][nt] = __builtin_amdgcn_mfma_f32_16x16x32_bf16(
                        afrag[mt][1], bfrag[nt][1], acc[mt][nt], 0, 0, 0);
                }

            // stage X_{it+1} into the OTHER buffer (no barrier needed: disjoint,
            // and every wave's afrag reads of sx_cur were issued above)
            if (pf) {
                ushort4v p0 = { f2bf(xv0.x), f2bf(xv0.y), f2bf(xv0.z), f2bf(xv0.w) };
                ushort4v p1 = { f2bf(xv1.x), f2bf(xv1.y), f2bf(xv1.z), f2bf(xv1.w) };
                *reinterpret_cast<ushort4v*>(&sx_nxt[o0s]) = p0;
                *reinterpret_cast<ushort4v*>(&sx_nxt[o1s]) = p1;
            }

            // C/D layout: element (reg r, lane) = Out[16*mt + quad*4 + r][16*nt + l]
            if (w < 2) {
                // Q,K: row-major [tok][e]
                unsigned short* __restrict__ dst = (w == 0) ? s_q : s_k;
                #pragma unroll
                for (int mt = 0; mt < 2; ++mt)
                    #pragma unroll
                    for (int nt = 0; nt < 4; ++nt)
                        #pragma unroll
                        for (int r = 0; r < 4; ++r) {
                            const int row = 16 * mt + quad * 4 + r;   // tok
                            dst[row * 64 + sw64(row, 2 * nt + (l >> 3)) * 8 + (l & 7)] =
                                f2bf(acc[mt][nt][r]);
                        }
            } else {
                // V,R: transposed [e][tok] -> reg index r contiguous -> packed 8B writes
                unsigned short* __restrict__ dstT = (w == 2) ? s_vt : s_rt;
                #pragma unroll
                for (int mt = 0; mt < 2; ++mt)
                    #pragma unroll
                    for (int nt = 0; nt < 4; ++nt) {
                        const int e = 16 * nt + l;
                        ushort4v pk = { f2bf(acc[mt][nt][0]), f2bf(acc[mt][nt][1]),
                                        f2bf(acc[mt][nt][2]), f2bf(acc[mt][nt][3]) };
                        *reinterpret_cast<ushort4v*>(
                            &dstT[e * 32 + sw32(e, 2 * mt + (quad >> 1)) * 8 + (quad & 1) * 4]) = pk;
                    }
            }
        }
        __syncthreads();                                  // B2: QKV(R) ready, afrag reads done

        // ---- phase 2: scores + exp. No max-subtraction, no cross-lane ops. ----
        {
            const int qrow = 16 * wmt + l;
            const short8 qa = *reinterpret_cast<const short8*>(
                &s_q[qrow * 64 + sw64(qrow, 4 * h + quad) * 8]);
            const short8 kb0 = *reinterpret_cast<const short8*>(
                &s_k[l * 64 + sw64(l, 4 * h + quad) * 8]);
            const short8 kb1 = *reinterpret_cast<const short8*>(
                &s_k[(16 + l) * 64 + sw64(16 + l, 4 * h + quad) * 8]);

            float4v s0 = (float4v){0.f, 0.f, 0.f, 0.f};
            float4v s1 = (float4v){0.f, 0.f, 0.f, 0.f};
            s0 = __builtin_amdgcn_mfma_f32_16x16x32_bf16(qa, kb0, s0, 0, 0, 0);
            s1 = __builtin_amdgcn_mfma_f32_16x16x32_bf16(qa, kb1, s1, 0, 0, 0);

            // row (16*wmt+quad*4+r): its 32 scores live in this quad's 16 lanes x {s0,s1}
            // P goes into sx_cur (X_it dead after afrag reads; publish guarded by B2)
            #pragma unroll
            for (int r = 0; r < 4; ++r) {
                const int rowG = h * kF + 16 * wmt + quad * 4 + r;
                sx_cur[rowG * 32 + sw32(rowG, l >> 3) * 8 + (l & 7)]       = f2bf(__expf(s0[r]));
                sx_cur[rowG * 32 + sw32(rowG, 2 + (l >> 3)) * 8 + (l & 7)] = f2bf(__expf(s1[r]));
            }
        }
        // NO barrier: phase 3 reads only P rows written by this same wave
        // (rows h*32+16*wmt .. +15); s_vt/s_rt were written before B2.

        // ---- phase 3: O_h = P_h @ V_h; rowsum via all-ones MFMA; +R, relu, store ----
        {
            const int prow = h * kF + 16 * wmt + l;
            const short8 pa = *reinterpret_cast<const short8*>(
                &sx_cur[prow * 32 + sw32(prow, quad) * 8]);
            const short8 vb0 = *reinterpret_cast<const short8*>(
                &s_vt[(32 * h + l) * 32 + sw32(32 * h + l, quad) * 8]);
            const short8 vb1 = *reinterpret_cast<const short8*>(
                &s_vt[(32 * h + 16 + l) * 32 + sw32(32 * h + 16 + l, quad) * 8]);
            const short8 ones = (short8)(short)0x3F80;   // bf16 1.0 splat

            float4v o0 = (float4v){0.f, 0.f, 0.f, 0.f};
            float4v o1 = (float4v){0.f, 0.f, 0.f, 0.f};
            float4v os = (float4v){0.f, 0.f, 0.f, 0.f};
            o0 = __builtin_amdgcn_mfma_f32_16x16x32_bf16(pa, vb0, o0, 0, 0, 0);
            o1 = __builtin_amdgcn_mfma_f32_16x16x32_bf16(pa, vb1, o1, 0, 0, 0);
            os = __builtin_amdgcn_mfma_f32_16x16x32_bf16(pa, ones, os, 0, 0, 0);  // row sums

            // residual: Rt[e][tok] -> reg index r contiguous -> packed 8B reads
            const ushort4v rA = *reinterpret_cast<const ushort4v*>(
                &s_rt[(32 * h + l) * 32 +
                      sw32(32 * h + l, 2 * wmt + (quad >> 1)) * 8 + (quad & 1) * 4]);
            const ushort4v rB = *reinterpret_cast<const ushort4v*>(
                &s_rt[(32 * h + 16 + l) * 32 +
                      sw32(32 * h + 16 + l, 2 * wmt + (quad >> 1)) * 8 + (quad & 1) * 4]);

            float* __restrict__ Ob = out + (size_t)b * (kF * kH);
            #pragma unroll
            for (int r = 0; r < 4; ++r) {
                const int f = 16 * wmt + quad * 4 + r;
                const float inv = __builtin_amdgcn_rcpf(os[r]);
                Ob[f * kH + 32 * h + l]      = fmaxf(o0[r] * inv + bf2f(rA[r]), 0.0f);
                Ob[f * kH + 32 * h + 16 + l] = fmaxf(o1[r] * inv + bf2f(rB[r]), 0.0f);
            }
        }
        cur ^= 1;
    }
}

extern "C" void kernel_launch(void* const* d_in, const int* in_sizes, int n_in,
                              void* d_out, int out_size, void* d_ws, size_t ws_size,
                              hipStream_t stream) {
    const float* X  = (const float*)d_in[0];
    const float* Wq = (const float*)d_in[1];
    const float* Wk = (const float*)d_in[2];
    const float* Wv = (const float*)d_in[3];
    const float* Wr = (const float*)d_in[4];
    float* out = (float*)d_out;
    unsigned short* wt = (unsigned short*)d_ws;   // 4*64*64*2 = 32 KiB

    wprep_kernel<<<4, 256, 0, stream>>>(Wq, Wk, Wv, Wr, wt);

    const int B = in_sizes[0] / (kF * kD);        // 16384
    interact_mfma<<<B / NB, 256, 0, stream>>>(X, wt, out);
}